// Round 15
// baseline (887.741 us; speedup 1.0000x reference)
//
#include <hip/hip_runtime.h>
#include <stdint.h>

#define Bn 32
#define Nn 1723
#define Cn 512
#define Hn 256
#define NK 54     // K-steps of 32 (K padded to 1728)

typedef __bf16 bf16x8 __attribute__((ext_vector_type(8)));
typedef float f32x4 __attribute__((ext_vector_type(4)));
typedef unsigned short u16;

__device__ __forceinline__ u16 f2b(float f){
  union{float f; uint32_t i;} c; c.f=f; uint32_t u=c.i;
  u += 0x7fffu + ((u>>16)&1u);
  return (u16)(u>>16);
}
__device__ __forceinline__ bf16x8 ld8(const u16* p){
  union{ uint4 u; bf16x8 b; } c;
  c.u = *reinterpret_cast<const uint4*>(p);
  return c.b;
}
__device__ __forceinline__ f32x4 mfma16(bf16x8 a, bf16x8 b, f32x4 c){
  return __builtin_amdgcn_mfma_f32_16x16x32_bf16(a,b,c,0,0,0);
}

// ---- kernel 0: weights -> bf16 MFMA-fragment-major (validated R5) ----
__global__ __launch_bounds__(256) void k_prep(
    const float* __restrict__ W1, const float* __restrict__ Wc, const float* __restrict__ W2,
    u16* __restrict__ W1f, u16* __restrict__ WcTf, u16* __restrict__ W2f)
{
  const int t = blockIdx.x*256 + threadIdx.x;
  const int lane = t & 63, unit = t >> 6;
  const int lr = lane & 15, lh = lane >> 4;
  const float* src; u16* dst; int K, tile, kk; bool tr = false;
  if (unit < 256){ tile = unit>>4; kk = unit&15; src = W1; dst = W1f; K = 512; }
  else if (unit < 384){ int u = unit-256; tile = u>>3; kk = u&7; src = Wc; dst = WcTf; K = 256; tr = true; }
  else { int u = unit-384; tile = u>>3; kk = u&7; src = W2; dst = W2f; K = 256; }
  const int row = tile*16 + lr;
  const int k0 = kk*32 + lh*8;
  union{u16 s[8]; uint4 u;} o;
  #pragma unroll
  for (int j=0;j<8;++j){
    float v = tr ? src[(size_t)(k0+j)*256 + row] : src[(size_t)row*K + k0 + j];
    o.s[j] = f2b(v);
  }
  *reinterpret_cast<uint4*>(dst + (size_t)(tile*(K/32)+kk)*512 + lane*8) = o.u;
}

// ---------------- stage A (validated; now per-pass over 8 b) ----------------
__global__ __launch_bounds__(256) void k_stageA(
    const float* __restrict__ x, const float* __restrict__ prw, const float* __restrict__ prb,
    const u16* __restrict__ W1f, const float* __restrict__ b1,
    const float* __restrict__ n1w, const float* __restrict__ n1b,
    const u16* __restrict__ WcTf, u16* __restrict__ supT, int bbase)
{
  __shared__ u16 t1[32*512];
  __shared__ float ps[2][32], pq[2][32];
  u16* const t2 = t1;
  const int bl = blockIdx.y;             // 0..7 (local b)
  const int b = bbase + bl;
  const int m0 = blockIdx.x*32;
  const int tid = threadIdx.x;
  const int w = tid>>6, l = tid&63, lr = l&15, lh = l>>4;
  const int wm = w>>1, wn = w&1;

  float pw[8], pb[8];
  #pragma unroll
  for (int j=0;j<8;++j){ pw[j]=prw[l*8+j]; pb[j]=prb[l*8+j]; }
  #pragma unroll
  for (int rr=0; rr<8; ++rr){
    const int rloc = w*8+rr;
    int rg = m0 + rloc; rg = rg < Nn ? rg : Nn-1;
    const float* src = x + ((size_t)b*Nn + rg)*Cn + l*8;
    float4 c0 = *reinterpret_cast<const float4*>(src);
    float4 c1 = *reinterpret_cast<const float4*>(src+4);
    float v[8] = {c0.x,c0.y,c0.z,c0.w,c1.x,c1.y,c1.z,c1.w};
    float s=0.f, q=0.f;
    #pragma unroll
    for (int j=0;j<8;++j){ s+=v[j]; q+=v[j]*v[j]; }
    #pragma unroll
    for (int m=1;m<64;m<<=1){ s += __shfl_xor(s,m); q += __shfl_xor(q,m); }
    const float mean = s*(1.f/Cn);
    const float rstd = rsqrtf(fmaxf(q*(1.f/Cn) - mean*mean, 0.f) + 1e-12f);
    union{uint4 u; u16 s[8];} ov;
    #pragma unroll
    for (int j=0;j<8;++j){
      float t = (v[j]-mean)*rstd*pw[j] + pb[j];
      ov.s[j] = f2b(fmaxf(t,0.f));
    }
    const int idx = (rloc*512 + l*8) ^ ((rloc&7)<<3);
    *reinterpret_cast<uint4*>(&t1[idx]) = ov.u;
  }
  __syncthreads();

  f32x4 acc[8];
  #pragma unroll
  for (int i=0;i<8;++i) acc[i] = f32x4{0.f,0.f,0.f,0.f};
  const int arow = wm*16 + lr;
  const int aswz = (arow&7)<<3;
  for (int kk=0; kk<16; ++kk){
    bf16x8 a = ld8(&t1[(arow*512 + kk*32 + lh*8) ^ aswz]);
    #pragma unroll
    for (int nt=0; nt<8; ++nt){
      bf16x8 bb = ld8(W1f + (size_t)(((wn*8+nt)*16 + kk))*512 + l*8);
      acc[nt] = mfma16(a, bb, acc[nt]);
    }
  }

  float sum[4]={0,0,0,0}, sq[4]={0,0,0,0};
  #pragma unroll
  for (int nt=0; nt<8; ++nt){
    const float bias = b1[wn*128+nt*16+lr];
    #pragma unroll
    for (int r=0;r<4;++r){
      float vv = acc[nt][r] + bias;
      acc[nt][r] = vv; sum[r]+=vv; sq[r]+=vv*vv;
    }
  }
  #pragma unroll
  for (int m=1;m<16;m<<=1){
    #pragma unroll
    for (int r=0;r<4;++r){ sum[r]+=__shfl_xor(sum[r],m); sq[r]+=__shfl_xor(sq[r],m); }
  }
  if (lr==0){
    #pragma unroll
    for (int r=0;r<4;++r){
      const int row = wm*16 + lh*4 + r;
      ps[wn][row]=sum[r]; pq[wn][row]=sq[r];
    }
  }
  __syncthreads();
  float mean[4], rstd[4];
  #pragma unroll
  for (int r=0;r<4;++r){
    const int row = wm*16 + lh*4 + r;
    const float S = ps[0][row]+ps[1][row];
    const float Q = pq[0][row]+pq[1][row];
    const float mu = S*(1.f/Hn);
    mean[r] = mu;
    rstd[r] = rsqrtf(fmaxf(Q*(1.f/Hn) - mu*mu, 0.f) + 1e-12f);
  }
  #pragma unroll
  for (int nt=0; nt<8; ++nt){
    const int col = wn*128+nt*16+lr;
    const float nw = n1w[col], nb = n1b[col];
    #pragma unroll
    for (int r=0;r<4;++r){
      const int row = wm*16 + lh*4 + r;
      float t = (acc[nt][r]-mean[r])*rstd[r]*nw + nb;
      t2[(row*256 + col) ^ ((row&7)<<3)] = f2b(fmaxf(t,0.f));
    }
  }
  __syncthreads();

  f32x4 acc2[8];
  #pragma unroll
  for (int i=0;i<8;++i) acc2[i] = f32x4{0.f,0.f,0.f,0.f};
  for (int kk=0; kk<8; ++kk){
    bf16x8 a = ld8(&t2[(arow*256 + kk*32 + lh*8) ^ aswz]);
    #pragma unroll
    for (int nt=0; nt<8; ++nt){
      bf16x8 bb = ld8(WcTf + (size_t)(((wn*8+nt)*8 + kk))*512 + l*8);
      acc2[nt] = mfma16(a, bb, acc2[nt]);
    }
  }

  const int off512 = (wm*2 + (lh>>1))*128 + lr*8 + (lh&1)*4;
  const int vbase = m0 + wm*16 + lh*4;
  #pragma unroll
  for (int nt=0; nt<8; ++nt){
    const int htile = wn*8 + nt;
    const size_t base = ((size_t)(bl*16 + htile)*NK + blockIdx.x)*512 + off512;
    ushort4 o;
    o.x = (vbase+0 < Nn) ? f2b(acc2[nt][0]) : (u16)0;
    o.y = (vbase+1 < Nn) ? f2b(acc2[nt][1]) : (u16)0;
    o.z = (vbase+2 < Nn) ? f2b(acc2[nt][2]) : (u16)0;
    o.w = (vbase+3 < Nn) ? f2b(acc2[nt][3]) : (u16)0;
    *reinterpret_cast<ushort4*>(supT + base) = o;
  }
}

// ---------------- adjT: adj f32 row-major -> adjF bf16 MFMA-fragment-major ----------------
// grid 864 = 8 local-b x 108 mtiles. Coalesced row reads -> LDS -> contiguous 1KB
// fragment writes. adjF frag (bl, mtile, kk): u16[lane*8+j] = adj[m0+(lane&15)][kk*32+(lane>>4)*8+j].
__global__ __launch_bounds__(256) void k_adjT(
    const float* __restrict__ adj, u16* __restrict__ adjF, int bbase)
{
  __shared__ u16 tile[16*1736];    // 54.25 KB; row stride 1736 (bank-rotating)
  const int bid = blockIdx.x;
  const int bl = bid & 7;
  const int b = bbase + bl;
  const int mtile = bid >> 3;      // 0..107
  const int m0 = mtile*16;
  const int tid = threadIdx.x;
  const float* adjb = adj + (size_t)b*Nn*Nn;

  for (int row=0; row<16; ++row){
    const int grow = m0 + row;
    const bool rok = grow < Nn;
    const float* rp = adjb + (size_t)(rok ? grow : 0)*Nn;
    #pragma unroll
    for (int j=0;j<7;++j){
      const int col = tid + j*256;
      if (col < 1728){
        float v = (rok && col < Nn) ? rp[col] : 0.f;
        tile[row*1736 + col] = f2b(v);
      }
    }
  }
  __syncthreads();

  const int l = tid & 63, w = tid >> 6, lr = l & 15, lh = l >> 4;
  const size_t fb = (size_t)(bl*108 + mtile)*NK;
  for (int kk = w; kk < NK; kk += 4){
    const u16* sp = &tile[lr*1736 + kk*32 + lh*8];
    uint4 v = *reinterpret_cast<const uint4*>(sp);
    *reinterpret_cast<uint4*>(adjF + (fb + kk)*512 + l*8) = v;
  }
}

// ---------------- stage B: BARRIER-FREE all-register GEMM1 + LN + GEMM2 ----------------
// grid 432 = 8 xcd(=local b) x 54 row-tiles of 32. 4 waves; wave w: GEMM1 cols w*64..+63.
// K-loop: 6 contiguous ld8 streams (2 adjF + 4 supT) + 8 MFMAs per kk. No LDS, no barriers.
__global__ __launch_bounds__(256) void k_stageB(
    const u16* __restrict__ adjF, const u16* __restrict__ supT,
    const float* __restrict__ cb, const float* __restrict__ n2w, const float* __restrict__ n2b,
    const u16* __restrict__ W2f, const float* __restrict__ bl2,
    const float* __restrict__ x, float* __restrict__ out, int bbase)
{
  __shared__ u16 t3[32*256];       // 16 KB
  __shared__ float ps[4][32], pq[4][32];
  const int bid = blockIdx.x;
  const int bl = bid & 7;          // local b == XCD (supT slice L2-resident)
  const int b = bbase + bl;
  const int t32 = bid >> 3;        // 0..53
  const int m0 = t32 * 32;
  const int tid = threadIdx.x, w = tid>>6, l = tid&63, lr = l&15, lh = l>>4;

  const u16* af0 = adjF + (size_t)(bl*108 + t32*2    )*NK*512 + l*8;
  const u16* af1 = adjF + (size_t)(bl*108 + t32*2 + 1)*NK*512 + l*8;
  const u16* sf  = supT + (size_t)(bl*16 + 4*w)*NK*512 + l*8;

  f32x4 acc1[2][4];
  #pragma unroll
  for (int i=0;i<2;++i)
    #pragma unroll
    for (int j=0;j<4;++j) acc1[i][j] = f32x4{0.f,0.f,0.f,0.f};

  #pragma unroll 3
  for (int kk=0; kk<NK; ++kk){
    bf16x8 a0 = ld8(af0 + (size_t)kk*512);
    bf16x8 a1 = ld8(af1 + (size_t)kk*512);
    bf16x8 b0 = ld8(sf + (size_t)(0*NK + kk)*512);
    bf16x8 b1 = ld8(sf + (size_t)(1*NK + kk)*512);
    bf16x8 b2 = ld8(sf + (size_t)(2*NK + kk)*512);
    bf16x8 b3 = ld8(sf + (size_t)(3*NK + kk)*512);
    acc1[0][0] = mfma16(a0, b0, acc1[0][0]);
    acc1[0][1] = mfma16(a0, b1, acc1[0][1]);
    acc1[0][2] = mfma16(a0, b2, acc1[0][2]);
    acc1[0][3] = mfma16(a0, b3, acc1[0][3]);
    acc1[1][0] = mfma16(a1, b0, acc1[1][0]);
    acc1[1][1] = mfma16(a1, b1, acc1[1][1]);
    acc1[1][2] = mfma16(a1, b2, acc1[1][2]);
    acc1[1][3] = mfma16(a1, b3, acc1[1][3]);
  }

  // ---- +conv_b, LN(256) across waves, relu -> t3 (validated R13 epilogue) ----
  float sum[2][4], sq[2][4];
  #pragma unroll
  for (int mt=0;mt<2;++mt)
    #pragma unroll
    for (int r=0;r<4;++r){ sum[mt][r]=0.f; sq[mt][r]=0.f; }
  float biasv[4];
  #pragma unroll
  for (int nt=0;nt<4;++nt) biasv[nt] = cb[w*64+nt*16+lr];
  #pragma unroll
  for (int mt=0;mt<2;++mt)
    #pragma unroll
    for (int nt=0;nt<4;++nt)
      #pragma unroll
      for (int r=0;r<4;++r){
        float vv = acc1[mt][nt][r] + biasv[nt];
        acc1[mt][nt][r] = vv; sum[mt][r]+=vv; sq[mt][r]+=vv*vv;
      }
  #pragma unroll
  for (int m=1;m<16;m<<=1){
    #pragma unroll
    for (int mt=0;mt<2;++mt)
      #pragma unroll
      for (int r=0;r<4;++r){ sum[mt][r]+=__shfl_xor(sum[mt][r],m); sq[mt][r]+=__shfl_xor(sq[mt][r],m); }
  }
  if (lr==0){
    #pragma unroll
    for (int mt=0;mt<2;++mt)
      #pragma unroll
      for (int r=0;r<4;++r){
        const int row = mt*16+lh*4+r;
        ps[w][row]=sum[mt][r]; pq[w][row]=sq[mt][r];
      }
  }
  __syncthreads();
  float meanv[2][4], rstdv[2][4];
  #pragma unroll
  for (int mt=0;mt<2;++mt)
    #pragma unroll
    for (int r=0;r<4;++r){
      const int row = mt*16+lh*4+r;
      const float S = ps[0][row]+ps[1][row]+ps[2][row]+ps[3][row];
      const float Q = pq[0][row]+pq[1][row]+pq[2][row]+pq[3][row];
      const float mu = S*(1.f/Hn);
      meanv[mt][r] = mu;
      rstdv[mt][r] = rsqrtf(fmaxf(Q*(1.f/Hn)-mu*mu, 0.f) + 1e-12f);
    }
  #pragma unroll
  for (int nt=0;nt<4;++nt){
    const int c2 = w*64+nt*16+lr;
    const float nw = n2w[c2], nb = n2b[c2];
    #pragma unroll
    for (int mt=0;mt<2;++mt)
      #pragma unroll
      for (int r=0;r<4;++r){
        const int row = mt*16+lh*4+r;
        float t = (acc1[mt][nt][r]-meanv[mt][r])*rstdv[mt][r]*nw + nb;
        t3[(row*256+c2) ^ ((row&7)<<3)] = f2b(fmaxf(t,0.f));
      }
  }
  __syncthreads();

  // ---- GEMM2 (two 64-col halves): y[32x512] = t3 @ lin2_W^T (K=256) + bias + x ----
  #pragma unroll
  for (int h=0; h<2; ++h){
    f32x4 acc2[2][4];
    #pragma unroll
    for (int i=0;i<2;++i)
      #pragma unroll
      for (int j=0;j<4;++j) acc2[i][j] = f32x4{0.f,0.f,0.f,0.f};
    for (int kk=0;kk<8;++kk){
      bf16x8 a[2];
      #pragma unroll
      for (int mt=0;mt<2;++mt){
        const int row = mt*16+lr;
        a[mt] = ld8(&t3[(row*256 + kk*32 + lh*8) ^ ((row&7)<<3)]);
      }
      #pragma unroll
      for (int nt=0;nt<4;++nt){
        bf16x8 bb = ld8(W2f + (size_t)(((w*8 + h*4 + nt)*8) + kk)*512 + l*8);
        #pragma unroll
        for (int mt=0;mt<2;++mt) acc2[mt][nt] = mfma16(a[mt], bb, acc2[mt][nt]);
      }
    }
    #pragma unroll
    for (int nt=0;nt<4;++nt){
      const int c2 = w*128 + h*64 + nt*16 + lr;
      const float bias = bl2[c2];
      #pragma unroll
      for (int mt=0;mt<2;++mt){
        #pragma unroll
        for (int r=0;r<4;++r){
          const int mg = m0 + mt*16 + lh*4 + r;
          if (mg < Nn){
            const size_t off = ((size_t)b*Nn + mg)*Cn + c2;
            out[off] = acc2[mt][nt][r] + bias + x[off];
          }
        }
      }
    }
  }
}

extern "C" void kernel_launch(void* const* d_in, const int* in_sizes, int n_in,
                              void* d_out, int out_size, void* d_ws, size_t ws_size,
                              hipStream_t stream){
  const float* x    = (const float*)d_in[0];
  const float* adj  = (const float*)d_in[1];
  const float* prw  = (const float*)d_in[2];
  const float* prb  = (const float*)d_in[3];
  const float* W1   = (const float*)d_in[4];
  const float* b1   = (const float*)d_in[5];
  const float* n1w  = (const float*)d_in[6];
  const float* n1b  = (const float*)d_in[7];
  const float* Wc   = (const float*)d_in[8];
  const float* cbv  = (const float*)d_in[9];
  const float* n2w  = (const float*)d_in[10];
  const float* n2b  = (const float*)d_in[11];
  const float* W2   = (const float*)d_in[12];
  const float* bl2  = (const float*)d_in[13];

  u16* ws    = (u16*)d_ws;
  u16* W1f   = ws;                                   // 131072 u16
  u16* WcTf  = ws + 131072;                          // 65536
  u16* W2f   = ws + 131072 + 65536;                  // 131072
  u16* supT  = ws + 327680;                          // 8*16*54*512   = 3,538,944 u16
  u16* adjF  = supT + (size_t)8*16*54*512;           // 8*108*54*512  = 23,887,872 u16
  // total ws use = 27,754,496 u16 = 55.5 MB (<= 57.3 MB proven in R12)

  k_prep<<<dim3(160), dim3(256), 0, stream>>>(W1, Wc, W2, W1f, WcTf, W2f);
  for (int p = 0; p < 4; ++p){
    const int bbase = p*8;
    k_stageA<<<dim3(NK,8), dim3(256), 0, stream>>>(x, prw, prb, W1f, b1, n1w, n1b, WcTf, supT, bbase);
    k_adjT<<<dim3(864), dim3(256), 0, stream>>>(adj, adjF, bbase);
    k_stageB<<<dim3(432), dim3(256), 0, stream>>>(adjF, supT, cbv, n2w, n2b, W2f, bl2, x, (float*)d_out, bbase);
  }
}

// Round 16
// 392.962 us; speedup vs baseline: 2.2591x; 2.2591x over previous
//
#include <hip/hip_runtime.h>
#include <stdint.h>

#define Bn 32
#define Nn 1723
#define Cn 512
#define Hn 256
#define MTA 54    // 32-k sub-steps (k padded to 1728)

typedef __bf16 bf16x8 __attribute__((ext_vector_type(8)));
typedef float f32x4 __attribute__((ext_vector_type(4)));
typedef unsigned short u16;

__device__ __forceinline__ u16 f2b(float f){
  union{float f; uint32_t i;} c; c.f=f; uint32_t u=c.i;
  u += 0x7fffu + ((u>>16)&1u);
  return (u16)(u>>16);
}
__device__ __forceinline__ bf16x8 ld8(const u16* p){
  union{ uint4 u; bf16x8 b; } c;
  c.u = *reinterpret_cast<const uint4*>(p);
  return c.b;
}
__device__ __forceinline__ f32x4 mfma16(bf16x8 a, bf16x8 b, f32x4 c){
  return __builtin_amdgcn_mfma_f32_16x16x32_bf16(a,b,c,0,0,0);
}
__device__ __forceinline__ bf16x8 cvt8(float4 a, float4 b){
  union{ uint32_t w[4]; bf16x8 v; } r;
  asm("v_cvt_pk_bf16_f32 %0, %1, %2" : "=v"(r.w[0]) : "v"(a.x), "v"(a.y));
  asm("v_cvt_pk_bf16_f32 %0, %1, %2" : "=v"(r.w[1]) : "v"(a.z), "v"(a.w));
  asm("v_cvt_pk_bf16_f32 %0, %1, %2" : "=v"(r.w[2]) : "v"(b.x), "v"(b.y));
  asm("v_cvt_pk_bf16_f32 %0, %1, %2" : "=v"(r.w[3]) : "v"(b.z), "v"(b.w));
  return r.v;
}
#define VMW(n)  asm volatile("s_waitcnt vmcnt(" #n ")" ::: "memory")
#define CFENCE() asm volatile("" ::: "memory")
#define GLD_LDS16(gp, lp) \
  __builtin_amdgcn_global_load_lds((const __attribute__((address_space(1))) void*)(gp), \
                                   (__attribute__((address_space(3))) void*)(lp), 16, 0, 0)

// ---- kernel 0: weights -> bf16 MFMA-fragment-major (validated R5) ----
__global__ __launch_bounds__(256) void k_prep(
    const float* __restrict__ W1, const float* __restrict__ Wc, const float* __restrict__ W2,
    u16* __restrict__ W1f, u16* __restrict__ WcTf, u16* __restrict__ W2f)
{
  const int t = blockIdx.x*256 + threadIdx.x;
  const int lane = t & 63, unit = t >> 6;
  const int lr = lane & 15, lh = lane >> 4;
  const float* src; u16* dst; int K, tile, kk; bool tr = false;
  if (unit < 256){ tile = unit>>4; kk = unit&15; src = W1; dst = W1f; K = 512; }
  else if (unit < 384){ int u = unit-256; tile = u>>3; kk = u&7; src = Wc; dst = WcTf; K = 256; tr = true; }
  else { int u = unit-384; tile = u>>3; kk = u&7; src = W2; dst = W2f; K = 256; }
  const int row = tile*16 + lr;
  const int k0 = kk*32 + lh*8;
  union{u16 s[8]; uint4 u;} o;
  #pragma unroll
  for (int j=0;j<8;++j){
    float v = tr ? src[(size_t)(k0+j)*256 + row] : src[(size_t)row*K + k0 + j];
    o.s[j] = f2b(v);
  }
  *reinterpret_cast<uint4*>(dst + (size_t)(tile*(K/32)+kk)*512 + lane*8) = o.u;
}

// ---------------- stage A (validated; phantom vertices ZEROED in supT) ----------------
__global__ __launch_bounds__(256) void k_stageA(
    const float* __restrict__ x, const float* __restrict__ prw, const float* __restrict__ prb,
    const u16* __restrict__ W1f, const float* __restrict__ b1,
    const float* __restrict__ n1w, const float* __restrict__ n1b,
    const u16* __restrict__ WcTf, u16* __restrict__ supT)
{
  __shared__ u16 t1[32*512];
  __shared__ float ps[2][32], pq[2][32];
  u16* const t2 = t1;
  const int b = blockIdx.y;
  const int m0 = blockIdx.x*32;
  const int tid = threadIdx.x;
  const int w = tid>>6, l = tid&63, lr = l&15, lh = l>>4;
  const int wm = w>>1, wn = w&1;

  float pw[8], pb[8];
  #pragma unroll
  for (int j=0;j<8;++j){ pw[j]=prw[l*8+j]; pb[j]=prb[l*8+j]; }
  #pragma unroll
  for (int rr=0; rr<8; ++rr){
    const int rloc = w*8+rr;
    int rg = m0 + rloc; rg = rg < Nn ? rg : Nn-1;
    const float* src = x + ((size_t)b*Nn + rg)*Cn + l*8;
    float4 c0 = *reinterpret_cast<const float4*>(src);
    float4 c1 = *reinterpret_cast<const float4*>(src+4);
    float v[8] = {c0.x,c0.y,c0.z,c0.w,c1.x,c1.y,c1.z,c1.w};
    float s=0.f, q=0.f;
    #pragma unroll
    for (int j=0;j<8;++j){ s+=v[j]; q+=v[j]*v[j]; }
    #pragma unroll
    for (int m=1;m<64;m<<=1){ s += __shfl_xor(s,m); q += __shfl_xor(q,m); }
    const float mean = s*(1.f/Cn);
    const float rstd = rsqrtf(fmaxf(q*(1.f/Cn) - mean*mean, 0.f) + 1e-12f);
    union{uint4 u; u16 s[8];} ov;
    #pragma unroll
    for (int j=0;j<8;++j){
      float t = (v[j]-mean)*rstd*pw[j] + pb[j];
      ov.s[j] = f2b(fmaxf(t,0.f));
    }
    const int idx = (rloc*512 + l*8) ^ ((rloc&7)<<3);
    *reinterpret_cast<uint4*>(&t1[idx]) = ov.u;
  }
  __syncthreads();

  f32x4 acc[8];
  #pragma unroll
  for (int i=0;i<8;++i) acc[i] = f32x4{0.f,0.f,0.f,0.f};
  const int arow = wm*16 + lr;
  const int aswz = (arow&7)<<3;
  for (int kk=0; kk<16; ++kk){
    bf16x8 a = ld8(&t1[(arow*512 + kk*32 + lh*8) ^ aswz]);
    #pragma unroll
    for (int nt=0; nt<8; ++nt){
      bf16x8 bb = ld8(W1f + (size_t)(((wn*8+nt)*16 + kk))*512 + l*8);
      acc[nt] = mfma16(a, bb, acc[nt]);
    }
  }

  float sum[4]={0,0,0,0}, sq[4]={0,0,0,0};
  #pragma unroll
  for (int nt=0; nt<8; ++nt){
    const float bias = b1[wn*128+nt*16+lr];
    #pragma unroll
    for (int r=0;r<4;++r){
      float vv = acc[nt][r] + bias;
      acc[nt][r] = vv; sum[r]+=vv; sq[r]+=vv*vv;
    }
  }
  #pragma unroll
  for (int m=1;m<16;m<<=1){
    #pragma unroll
    for (int r=0;r<4;++r){ sum[r]+=__shfl_xor(sum[r],m); sq[r]+=__shfl_xor(sq[r],m); }
  }
  if (lr==0){
    #pragma unroll
    for (int r=0;r<4;++r){
      const int row = wm*16 + lh*4 + r;
      ps[wn][row]=sum[r]; pq[wn][row]=sq[r];
    }
  }
  __syncthreads();
  float mean[4], rstd[4];
  #pragma unroll
  for (int r=0;r<4;++r){
    const int row = wm*16 + lh*4 + r;
    const float S = ps[0][row]+ps[1][row];
    const float Q = pq[0][row]+pq[1][row];
    const float mu = S*(1.f/Hn);
    mean[r] = mu;
    rstd[r] = rsqrtf(fmaxf(Q*(1.f/Hn) - mu*mu, 0.f) + 1e-12f);
  }
  #pragma unroll
  for (int nt=0; nt<8; ++nt){
    const int col = wn*128+nt*16+lr;
    const float nw = n1w[col], nb = n1b[col];
    #pragma unroll
    for (int r=0;r<4;++r){
      const int row = wm*16 + lh*4 + r;
      float t = (acc[nt][r]-mean[r])*rstd[r]*nw + nb;
      t2[(row*256 + col) ^ ((row&7)<<3)] = f2b(fmaxf(t,0.f));
    }
  }
  __syncthreads();

  f32x4 acc2[8];
  #pragma unroll
  for (int i=0;i<8;++i) acc2[i] = f32x4{0.f,0.f,0.f,0.f};
  for (int kk=0; kk<8; ++kk){
    bf16x8 a = ld8(&t2[(arow*256 + kk*32 + lh*8) ^ aswz]);
    #pragma unroll
    for (int nt=0; nt<8; ++nt){
      bf16x8 bb = ld8(WcTf + (size_t)(((wn*8+nt)*8 + kk))*512 + l*8);
      acc2[nt] = mfma16(a, bb, acc2[nt]);
    }
  }

  const int off512 = (wm*2 + (lh>>1))*128 + lr*8 + (lh&1)*4;
  const int vbase = m0 + wm*16 + lh*4;
  #pragma unroll
  for (int nt=0; nt<8; ++nt){
    const int htile = wn*8 + nt;
    const size_t base = ((size_t)(b*16 + htile)*MTA + blockIdx.x)*512 + off512;
    ushort4 o;
    o.x = (vbase+0 < Nn) ? f2b(acc2[nt][0]) : (u16)0;
    o.y = (vbase+1 < Nn) ? f2b(acc2[nt][1]) : (u16)0;
    o.z = (vbase+2 < Nn) ? f2b(acc2[nt][2]) : (u16)0;
    o.w = (vbase+3 < Nn) ? f2b(acc2[nt][3]) : (u16)0;
    *reinterpret_cast<ushort4*>(supT + base) = o;
  }
}

// ---------------- stage B: K-128 row-contiguous gll, 3-buf adj + 4-set bv, deep FIFO ----------------
// grid 1728 = 8 XCD x (4 b x 54 tiles of 32 rows). 4 waves.
// FIFO invariant (hand-traced): all bv(s+1) issued BEFORE G(s+2); every bv-consume wait
// is vmcnt(16), top-of-step wait VMW(20) -> adj prefetch (G(s+1),G(s+2)) NEVER drains.
__global__ __launch_bounds__(256) void k_stageB(
    const float* __restrict__ adj, const u16* __restrict__ supT,
    const float* __restrict__ cb, const float* __restrict__ n2w, const float* __restrict__ n2b,
    const u16* __restrict__ W2f, const float* __restrict__ bl2,
    const float* __restrict__ x, float* __restrict__ out)
{
  __shared__ float abuf[3][4096];    // 48 KB: 3 bufs x 32 rows x 128 f32, 16B-granule XOR(row&7)
  __shared__ float ps[4][32], pq[4][32];
  u16* const t3 = (u16*)&abuf[0][0]; // 16 KB alias after K-loop
  const int bid = blockIdx.x;
  const int xcd = bid & 7, idx = bid >> 3;
  const int b = xcd*4 + (idx & 3);          // 4 consecutive b per XCD (supT L2-resident)
  const int m0 = (idx >> 2) * 32;
  const int tid = threadIdx.x, w = tid>>6, l = tid&63, lr = l&15, lh = l>>4;

  const float* adjb = adj + (size_t)b*Nn*Nn;
  const u16* supb = supT + (size_t)b*16*MTA*512;
  const float* gmax = adj + ((size_t)Bn*Nn*Nn - 4);

  // gll sources (validated R11 geometry): gll g covers local rows 8w+2g, 8w+2g+1
  const float *gb0, *gb1, *gb2, *gb3;
  {
    const int sb = l & 31;
    #define MKGB(g, dst) { int rl = 8*w + 2*(g) + (l>>5); int rg = m0 + rl; \
                           if (rg > Nn-1) rg = Nn-1; \
                           dst = adjb + (size_t)rg*Nn + ((sb ^ (rl&7))<<2); }
    MKGB(0, gb0) MKGB(1, gb1) MKGB(2, gb2) MKGB(3, gb3)
    #undef MKGB
  }

  bf16x8 bvA[4], bvB[4], bvC[4], bvD[4];
  f32x4 acc1[2][4];
  #pragma unroll
  for (int i=0;i<2;++i)
    #pragma unroll
    for (int j=0;j<4;++j) acc1[i][j] = f32x4{0.f,0.f,0.f,0.f};

  #define GISSUE(buf, s) do{                                             \
    const float* g0 = gb0 + (size_t)(s)*128; if (g0 > gmax) g0 = gmax;   \
    const float* g1 = gb1 + (size_t)(s)*128; if (g1 > gmax) g1 = gmax;   \
    const float* g2 = gb2 + (size_t)(s)*128; if (g2 > gmax) g2 = gmax;   \
    const float* g3 = gb3 + (size_t)(s)*128; if (g3 > gmax) g3 = gmax;   \
    GLD_LDS16(g0, &abuf[buf][(8*w+0)*128]);                              \
    GLD_LDS16(g1, &abuf[buf][(8*w+2)*128]);                              \
    GLD_LDS16(g2, &abuf[buf][(8*w+4)*128]);                              \
    GLD_LDS16(g3, &abuf[buf][(8*w+6)*128]);                              \
  }while(0)

  #define BVL(set, i32) do{                                              \
    const int sb_ = (i32) > 53 ? 53 : (i32);                             \
    _Pragma("unroll")                                                    \
    for (int nt=0;nt<4;++nt)                                             \
      set[nt] = ld8(supb + (size_t)((w*4+nt)*MTA + sb_)*512 + l*8);      \
  }while(0)

  #define MSUB(buf, kk, set) do{                                         \
    _Pragma("unroll")                                                    \
    for (int mt=0;mt<2;++mt){                                            \
      const int row = mt*16 + lr;                                        \
      const int o0 = row*128 + ((((kk)*8 + lh*2) ^ (row&7))<<2);         \
      float4 A  = *reinterpret_cast<const float4*>(&abuf[buf][o0]);      \
      float4 Bv = *reinterpret_cast<const float4*>(&abuf[buf][o0^4]);    \
      bf16x8 af = cvt8(A, Bv);                                           \
      _Pragma("unroll")                                                  \
      for (int nt=0;nt<4;++nt) acc1[mt][nt] = mfma16(af, set[nt], acc1[mt][nt]); \
    }                                                                    \
  }while(0)

  // ---- prologue: FIFO = [G(0)4, bv(0)16, G(1)4] = 24 outstanding ----
  GISSUE(0, 0); CFENCE();
  BVL(bvA, 0); BVL(bvB, 1); BVL(bvC, 2); BVL(bvD, 3); CFENCE();
  GISSUE(1, 1); CFENCE();

  // ---- 13 full steps; step s reads buf s%3, consumes bv idx 4s..4s+3 ----
  #pragma unroll 1
  for (int s=0; s<13; ++s){
    const int buf = s % 3;
    VMW(20); __builtin_amdgcn_s_barrier(); CFENCE();   // G(s) landed; keeps bv(s)16+G(s+1)4
    MSUB(buf, 0, bvA);  BVL(bvA, 4*s+4); CFENCE();
    MSUB(buf, 1, bvB);  BVL(bvB, 4*s+5); CFENCE();
    MSUB(buf, 2, bvC);  BVL(bvC, 4*s+6); CFENCE();
    MSUB(buf, 3, bvD);  BVL(bvD, 4*s+7); CFENCE();
    if (s < 12){ GISSUE((s+2)%3, s+2); CFENCE(); }
  }
  // ---- tail step 13 (buf 1): k 1664..1727 => subs 0,1 only ----
  VMW(16); __builtin_amdgcn_s_barrier(); CFENCE();     // G(13) landed; keeps bv(13)16
  MSUB(1, 0, bvA);
  MSUB(1, 1, bvB);
  asm volatile("s_waitcnt vmcnt(0) lgkmcnt(0)" ::: "memory");
  __builtin_amdgcn_s_barrier(); CFENCE();              // abuf lifetime over (t3 alias safe)

  // ---- +conv_b, LN(256) across waves, relu -> t3 (validated epilogue) ----
  float sum[2][4], sq[2][4];
  #pragma unroll
  for (int mt=0;mt<2;++mt)
    #pragma unroll
    for (int r=0;r<4;++r){ sum[mt][r]=0.f; sq[mt][r]=0.f; }
  float biasv[4];
  #pragma unroll
  for (int nt=0;nt<4;++nt) biasv[nt] = cb[w*64+nt*16+lr];
  #pragma unroll
  for (int mt=0;mt<2;++mt)
    #pragma unroll
    for (int nt=0;nt<4;++nt)
      #pragma unroll
      for (int r=0;r<4;++r){
        float vv = acc1[mt][nt][r] + biasv[nt];
        acc1[mt][nt][r] = vv; sum[mt][r]+=vv; sq[mt][r]+=vv*vv;
      }
  #pragma unroll
  for (int m=1;m<16;m<<=1){
    #pragma unroll
    for (int mt=0;mt<2;++mt)
      #pragma unroll
      for (int r=0;r<4;++r){ sum[mt][r]+=__shfl_xor(sum[mt][r],m); sq[mt][r]+=__shfl_xor(sq[mt][r],m); }
  }
  if (lr==0){
    #pragma unroll
    for (int mt=0;mt<2;++mt)
      #pragma unroll
      for (int r=0;r<4;++r){
        const int row = mt*16+lh*4+r;
        ps[w][row]=sum[mt][r]; pq[w][row]=sq[mt][r];
      }
  }
  __syncthreads();
  float meanv[2][4], rstdv[2][4];
  #pragma unroll
  for (int mt=0;mt<2;++mt)
    #pragma unroll
    for (int r=0;r<4;++r){
      const int row = mt*16+lh*4+r;
      const float S = ps[0][row]+ps[1][row]+ps[2][row]+ps[3][row];
      const float Q = pq[0][row]+pq[1][row]+pq[2][row]+pq[3][row];
      const float mu = S*(1.f/Hn);
      meanv[mt][r] = mu;
      rstdv[mt][r] = rsqrtf(fmaxf(Q*(1.f/Hn)-mu*mu, 0.f) + 1e-12f);
    }
  #pragma unroll
  for (int nt=0;nt<4;++nt){
    const int c2 = w*64+nt*16+lr;
    const float nw = n2w[c2], nb = n2b[c2];
    #pragma unroll
    for (int mt=0;mt<2;++mt)
      #pragma unroll
      for (int r=0;r<4;++r){
        const int row = mt*16+lh*4+r;
        float t = (acc1[mt][nt][r]-meanv[mt][r])*rstdv[mt][r]*nw + nb;
        t3[(row*256+c2) ^ ((row&7)<<3)] = f2b(fmaxf(t,0.f));
      }
  }
  __syncthreads();

  // ---- GEMM2 (two 64-col halves): y[32x512] = t3 @ lin2_W^T (K=256) + bias + x ----
  #pragma unroll
  for (int h=0; h<2; ++h){
    f32x4 acc2[2][4];
    #pragma unroll
    for (int i=0;i<2;++i)
      #pragma unroll
      for (int j=0;j<4;++j) acc2[i][j] = f32x4{0.f,0.f,0.f,0.f};
    for (int kk=0;kk<8;++kk){
      bf16x8 a[2];
      #pragma unroll
      for (int mt=0;mt<2;++mt){
        const int row = mt*16+lr;
        a[mt] = ld8(&t3[(row*256 + kk*32 + lh*8) ^ ((row&7)<<3)]);
      }
      #pragma unroll
      for (int nt=0;nt<4;++nt){
        bf16x8 bb = ld8(W2f + (size_t)(((w*8 + h*4 + nt)*8) + kk)*512 + l*8);
        #pragma unroll
        for (int mt=0;mt<2;++mt) acc2[mt][nt] = mfma16(a[mt], bb, acc2[mt][nt]);
      }
    }
    #pragma unroll
    for (int nt=0;nt<4;++nt){
      const int c2 = w*128 + h*64 + nt*16 + lr;
      const float bias = bl2[c2];
      #pragma unroll
      for (int mt=0;mt<2;++mt){
        #pragma unroll
        for (int r=0;r<4;++r){
          const int mg = m0 + mt*16 + lh*4 + r;
          if (mg < Nn){
            const size_t off = ((size_t)b*Nn + mg)*Cn + c2;
            out[off] = acc2[mt][nt][r] + bias + x[off];
          }
        }
      }
    }
  }
  #undef GISSUE
  #undef BVL
  #undef MSUB
}

extern "C" void kernel_launch(void* const* d_in, const int* in_sizes, int n_in,
                              void* d_out, int out_size, void* d_ws, size_t ws_size,
                              hipStream_t stream){
  const float* x    = (const float*)d_in[0];
  const float* adj  = (const float*)d_in[1];
  const float* prw  = (const float*)d_in[2];
  const float* prb  = (const float*)d_in[3];
  const float* W1   = (const float*)d_in[4];
  const float* b1   = (const float*)d_in[5];
  const float* n1w  = (const float*)d_in[6];
  const float* n1b  = (const float*)d_in[7];
  const float* Wc   = (const float*)d_in[8];
  const float* cbv  = (const float*)d_in[9];
  const float* n2w  = (const float*)d_in[10];
  const float* n2b  = (const float*)d_in[11];
  const float* W2   = (const float*)d_in[12];
  const float* bl2  = (const float*)d_in[13];

  u16* ws    = (u16*)d_ws;
  u16* W1f   = ws;                           // 131072 u16
  u16* WcTf  = ws + 131072;                  // 65536
  u16* W2f   = ws + 131072 + 65536;          // 131072
  u16* supT  = ws + 131072 + 65536 + 131072; // 32*16*54*512 u16 (~28.3 MB)

  k_prep<<<dim3(160), dim3(256), 0, stream>>>(W1, Wc, W2, W1f, WcTf, W2f);
  k_stageA<<<dim3(MTA,Bn), dim3(256), 0, stream>>>(x, prw, prb, W1f, b1, n1w, n1b, WcTf, supT);
  k_stageB<<<dim3(54*Bn), dim3(256), 0, stream>>>(adj, supT, cbv, n2w, n2b, W2f, bl2, x, (float*)d_out);
}